// Round 15
// baseline (155.694 us; speedup 1.0000x reference)
//
#include <hip/hip_runtime.h>
#include <stdint.h>

// LinearBin: out = x @ sign(W)^T + bias   (B=131072, IN=OUT=512, fp32)
// v15: v13's strict-FIFO DMA pipeline at half tile width so the ladder fits
//      4 waves/SIMD (2 blocks/CU). Wave tile 64x32: acc 32 AGPR + B-dbuf 32
//      VGPR. Twin col-half blocks XCD-paired via dispatch remap (x L2 reuse).
//      3 chunk-DMAs in flight (ladder: B(ck+1),DMA(ck+2) at epoch top;
//      vmcnt 12/10/4). 16-slot swizzle (verified 0-conflict), setprio MFMA.

#define BATCH   131072
#define IN_F    512
#define OUT_F   512
#define BM      64
#define NCH     8             // K-chunks of 64 floats (4 mfma k-steps each)
#define BUFB    16384         // bytes per ring buffer

using f32x4  = __attribute__((ext_vector_type(4))) float;
using f32x16 = __attribute__((ext_vector_type(16))) float;
using short8 = __attribute__((ext_vector_type(8))) short;
using usv8   = __attribute__((ext_vector_type(8))) unsigned short;
using u32    = uint32_t;

// ---------------- prep: binarize W into 32x32x16-fragment-major bf16 --------
// (verified r6/r8)  wf[((kt*16+nf)*64+l)*8+j] = sign(W[nf*32+(l&31)][kt*16+(l>>5)*8+j])
__global__ void prep_w(const float* __restrict__ W, unsigned short* __restrict__ wf) {
    int t = blockIdx.x * blockDim.x + threadIdx.x; // 32768 threads
    int l  = t & 63;
    int nf = (t >> 6) & 15;
    int kt = t >> 10;
    int n = nf * 32 + (l & 31);
    int k = kt * 16 + ((l >> 5) << 3);
    const float* src = W + (size_t)n * IN_F + k;
    f32x4 w0 = *(const f32x4*)(src);
    f32x4 w1 = *(const f32x4*)(src + 4);
    usv8 o;
#pragma unroll
    for (int j = 0; j < 4; ++j) {
        o[j]     = (w0[j] >= 0.0f) ? 0x3F80u : 0xBF80u; // +1.0 / -1.0 bf16
        o[j + 4] = (w1[j] >= 0.0f) ? 0x3F80u : 0xBF80u;
    }
    *(usv8*)(wf + (size_t)t * 8) = o;
}

// ---------------- GEMM ----------------
__global__ __launch_bounds__(512, 4) void gemm_bin(
    const float* __restrict__ X, const unsigned short* __restrict__ WF,
    const float* __restrict__ bias, float* __restrict__ out) {

    // ring of 4 fp32 chunks: [64 rows][256B], 16B slots XOR-swizzled by row&15
    __shared__ __align__(16) char smem[4 * BUFB];   // 64KB -> 2 blocks/CU

    const int tid  = threadIdx.x;
    const int lane = tid & 63;
    const int wv   = tid >> 6;              // 0..7 -> 32-col slice of the half

    // dispatch remap: d -> (strip, half); twins (strip,0/1) are 8 dispatch
    // indices apart -> same XCD, near-adjacent in time -> x L2-shared.
    const int d     = blockIdx.x;           // grid = 4096
    const int strip = ((d >> 4) << 3) | (d & 7);
    const int half  = (d >> 3) & 1;
    const int m0    = strip * BM;
    const int col0  = half * 256 + wv * 32;

    // ---- DMA source geometry (2 x 16B per thread per chunk; v13-verified) ----
    const int dr   = wv * 4 + (lane >> 4);
    const int ds4  = ((lane & 15) ^ (dr & 15)) << 2;
    const float* src0 = X + (size_t)(m0 + dr) * IN_F + ds4;
    const float* src1 = src0 + (size_t)32 * IN_F;

#define ISSUE_DMA(ck_)                                                         \
    {                                                                          \
        char* b_ = smem + ((ck_) & 3) * BUFB + wv * 1024;                      \
        __builtin_amdgcn_global_load_lds(                                      \
            (const __attribute__((address_space(1))) void*)(src0 + (ck_) * 64),\
            (__attribute__((address_space(3))) void*)(b_), 16, 0, 0);          \
        __builtin_amdgcn_global_load_lds(                                      \
            (const __attribute__((address_space(1))) void*)(src1 + (ck_) * 64),\
            (__attribute__((address_space(3))) void*)(b_ + 8192), 16, 0, 0);   \
    }

    // ---- B: fragment-major, nf = half*8 + wv (one 32-col frag per kt) ----
    const short8* wb = (const short8*)(WF) + ((size_t)(half * 8 + wv) * 64 + lane);
    short8 bf[2][4];
#define LDB_ALL(bi_, ck_)                                                      \
    {                                                                          \
        _Pragma("unroll")                                                      \
        for (int g = 0; g < 4; ++g)                                            \
            bf[bi_][g] = wb[((ck_) * 4 + g) * 1024];                           \
    }

    // ---- A-frag: row rg*32+(l&31), floats kt4*16+(l>>5)*8 (v13-verified) ----
    const int arow = (lane & 31) * 256;
    const int aq32 = (lane >> 5) << 5;
    const int aswz = (lane & 15) << 4;

#define LDA_CVT(dst, ab_, kt4_)                                                \
    {                                                                          \
        _Pragma("unroll")                                                      \
        for (int rg = 0; rg < 2; ++rg) {                                       \
            const char* p_  = (ab_) + rg * 8192 + arow;                        \
            const int  blo_ = (((kt4_) << 6) + aq32) ^ aswz;                   \
            f32x4 lo_ = *(const f32x4*)(p_ + blo_);                            \
            f32x4 hi_ = *(const f32x4*)(p_ + (blo_ ^ 16));                     \
            u32 w0_, w1_, w2_, w3_;                                            \
            asm("v_cvt_pk_bf16_f32 %0, %1, %2" : "=v"(w0_)                     \
                : "v"(lo_[0]), "v"(lo_[1]));                                   \
            asm("v_cvt_pk_bf16_f32 %0, %1, %2" : "=v"(w1_)                     \
                : "v"(lo_[2]), "v"(lo_[3]));                                   \
            asm("v_cvt_pk_bf16_f32 %0, %1, %2" : "=v"(w2_)                     \
                : "v"(hi_[0]), "v"(hi_[1]));                                   \
            asm("v_cvt_pk_bf16_f32 %0, %1, %2" : "=v"(w3_)                     \
                : "v"(hi_[2]), "v"(hi_[3]));                                   \
            union { u32 w[4]; short8 v; } pk_;                                 \
            pk_.w[0] = w0_; pk_.w[1] = w1_; pk_.w[2] = w2_; pk_.w[3] = w3_;    \
            dst[rg] = pk_.v;                                                   \
        }                                                                      \
    }

    // ---- bias -> accumulator init (col = lane&31, same for all elements) ----
    const float bv = bias[col0 + (lane & 31)];
    f32x16 acc[2];
#pragma unroll
    for (int rg = 0; rg < 2; ++rg)
#pragma unroll
        for (int r = 0; r < 16; ++r) acc[rg][r] = bv;
    __builtin_amdgcn_sched_barrier(0);

    // ---- prologue FIFO ladder: D0, B0, D1 ----
    ISSUE_DMA(0);
    __builtin_amdgcn_sched_barrier(0);
    LDB_ALL(0, 0);
    __builtin_amdgcn_sched_barrier(0);
    ISSUE_DMA(1);
    __builtin_amdgcn_sched_barrier(0);

#pragma unroll
    for (int ck = 0; ck < NCH; ++ck) {
        // epoch top: keep ladder order  ... B(ck+1), DMA(ck+2) ...
        if (ck + 1 < NCH) LDB_ALL((ck + 1) & 1, ck + 1);
        __builtin_amdgcn_sched_barrier(0);
        if (ck + 2 < NCH) ISSUE_DMA(ck + 2);   // 3-deep; buf (ck-2)&3 is free
        __builtin_amdgcn_sched_barrier(0);
        // retire exactly DMA(ck):
        // ck<=5: D(ck)2+B(ck)4+D(ck+1)2+B(ck+1)4+D(ck+2)2 = 14 -> vmcnt(12)
        // ck==6: D6:2+B6:4+D7:2+B7:4 = 12 -> vmcnt(10);  ck==7: 6 -> vmcnt(4)
        if (ck < NCH - 2)      asm volatile("s_waitcnt vmcnt(12)" ::: "memory");
        else if (ck == NCH - 2) asm volatile("s_waitcnt vmcnt(10)" ::: "memory");
        else                    asm volatile("s_waitcnt vmcnt(4)"  ::: "memory");
        __builtin_amdgcn_sched_barrier(0);
        __builtin_amdgcn_s_barrier();
        __builtin_amdgcn_sched_barrier(0);

        // compute chunk ck (B(ck) is now FIFO-oldest; its waits retire only it)
        const char* ab = smem + (ck & 3) * BUFB;
        short8 af[2];
#pragma unroll
        for (int kt4 = 0; kt4 < 4; ++kt4) {
            LDA_CVT(af, ab, kt4);
            __builtin_amdgcn_s_setprio(1);
#pragma unroll
            for (int rg = 0; rg < 2; ++rg)
                acc[rg] = __builtin_amdgcn_mfma_f32_32x32x16_bf16(
                    af[rg], bf[ck & 1][kt4], acc[rg], 0, 0, 0);
            __builtin_amdgcn_s_setprio(0);
        }
    }
#undef ISSUE_DMA
#undef LDB_ALL
#undef LDA_CVT

    // ---- epilogue: direct stores (bias already in acc) ----
    // C/D: col = lane&31, row = (r&3) + 8*(r>>2) + 4*(lane>>5)
    const int c     = lane & 31;
    const int rbase = (lane >> 5) << 2;
#pragma unroll
    for (int rg = 0; rg < 2; ++rg)
#pragma unroll
        for (int r = 0; r < 16; ++r) {
            const int row = rg * 32 + (r & 3) + 8 * (r >> 2) + rbase;
            out[(size_t)(m0 + row) * OUT_F + col0 + c] = acc[rg][r];
        }
}

extern "C" void kernel_launch(void* const* d_in, const int* in_sizes, int n_in,
                              void* d_out, int out_size, void* d_ws, size_t ws_size,
                              hipStream_t stream) {
    const float* X    = (const float*)d_in[0];
    const float* W    = (const float*)d_in[1];
    const float* bias = (const float*)d_in[2];
    float* o          = (float*)d_out;
    unsigned short* wf = (unsigned short*)d_ws; // 512KB fragment-major binarized W

    hipLaunchKernelGGL(prep_w, dim3(128), dim3(256), 0, stream, W, wf);
    hipLaunchKernelGGL(gemm_bin, dim3((BATCH / BM) * 2), dim3(512), 0, stream,
                       X, wf, bias, o);
}